// Round 7
// baseline (221.585 us; speedup 1.0000x reference)
//
#include <hip/hip_runtime.h>
#include <hip/hip_bf16.h>
#include <stdint.h>

#define S_LEN 1024
#define HDIM  1024
#define NHEADS 16
#define HEAD_D 64
#define KSEL  512
#define BATCH 8

typedef unsigned short ushort_t;
typedef __attribute__((ext_vector_type(8))) __bf16 bf16x8;
typedef __attribute__((ext_vector_type(4))) float  f32x4;

typedef const __attribute__((address_space(1))) void cg_void;
typedef __attribute__((address_space(3))) void lds_void;

__device__ __forceinline__ void gl_lds16(const void* g, void* l) {
    __builtin_amdgcn_global_load_lds((cg_void*)g, (lds_void*)l, 16, 0, 0);
}

// round-to-nearest-even f32 -> bf16 (finite inputs only)
__device__ __forceinline__ ushort_t f2bf(float f) {
    union { float f; unsigned int i; } x; x.f = f;
    unsigned int r = (x.i + 0x7fffu + ((x.i >> 16) & 1u)) >> 16;
    return (ushort_t)r;
}

// ---------------- kernel 0: prep = cvt(hidden,Wq,Wk,Wv) + compact -----------
// blocks 0..2815: fp32->bf16 (1024 thr x 1 float4). blocks 2816..2823: compact.
__global__ __launch_bounds__(1024) void prep_kernel(
    const float* __restrict__ hidden, const float* __restrict__ wq,
    const float* __restrict__ wk, const float* __restrict__ wv,
    const int* __restrict__ remain,
    ushort_t* __restrict__ hbf, ushort_t* __restrict__ wqb,
    ushort_t* __restrict__ wkb, ushort_t* __restrict__ wvb,
    int* __restrict__ idx, int* __restrict__ valid) {
    __shared__ int wsum[16];
    __shared__ int woff[17];
    int blk = blockIdx.x;
    if (blk < 2816) {
        const float* s; ushort_t* d; int base;
        if (blk < 2048)      { s = hidden; d = hbf; base = blk; }
        else if (blk < 2304) { s = wq; d = wqb; base = blk - 2048; }
        else if (blk < 2560) { s = wk; d = wkb; base = blk - 2304; }
        else                 { s = wv; d = wvb; base = blk - 2560; }
        int i = base * 1024 + threadIdx.x;
        float4 v = ((const float4*)s)[i];
        ushort4 o;
        o.x = f2bf(v.x); o.y = f2bf(v.y); o.z = f2bf(v.z); o.w = f2bf(v.w);
        ((ushort4*)d)[i] = o;
    } else {
        int b = blk - 2816, t = threadIdx.x;
        int r = remain[b * S_LEN + t];
        unsigned long long m = __ballot(r != 0);
        int lane = t & 63, w = t >> 6;
        int pre = __popcll(m & ((1ull << lane) - 1ull));
        if (lane == 0) wsum[w] = __popcll(m);
        __syncthreads();
        if (t == 0) { int a = 0; for (int i = 0; i < 16; i++) { woff[i] = a; a += wsum[i]; } woff[16] = a; }
        __syncthreads();
        int tot = woff[16];
        int onesBefore = woff[w] + pre;
        int slot = r ? onesBefore : (tot + (t - onesBefore));
        if (slot < KSEL) { idx[b * KSEL + slot] = t; valid[b * KSEL + slot] = r; }
    }
}

// ---------------- kernel 1: fused K/V/Q projection GEMM ---------------------
// flat grid 1280. blocks 0..1023: C[8192][2048] = hbf @ [Wk;Wv]^T, XCD-swizzled
// (i&7 = XCD; each XCD owns 8 A-strips -> A fetched on one XCD only).
// n<1024 -> kp (K); n>=1024 -> vt (V^T via 2-pass LDS transpose, coalesced).
// blocks 1024..1279: Q on gathered rows, epilogue (acc*valid + bq)*QSCALE.
// QSCALE folds 1/sqrt(64) and log2(e) (attn uses exp2).
#define QSCALE 0.1803368801111244f
#define LT_PITCH 136
__global__ __launch_bounds__(256, 5) void gemm_fused(
    const ushort_t* __restrict__ hbf, const ushort_t* __restrict__ wkv,
    const ushort_t* __restrict__ wq,
    const float* __restrict__ bk, const float* __restrict__ bv,
    const float* __restrict__ bq,
    const int* __restrict__ idx, const int* __restrict__ valid,
    ushort_t* __restrict__ kp, ushort_t* __restrict__ vt, ushort_t* __restrict__ qp) {
    __shared__ __align__(16) ushort_t pool[64 * LT_PITCH];   // 17408 B
    ushort_t* As = pool;           // 4096 elems
    ushort_t* Bs = pool + 4096;    // 4096 elems
    const int i = blockIdx.x;
    int z, bmI, bnI;
    if (i < 1024) { z = 0; int x = i & 7, j = i >> 3; bmI = x * 8 + (j >> 4); bnI = j & 15; }
    else          { z = 1; int q = i - 1024;          bmI = q >> 3;           bnI = q & 7;  }
    const long bm = (long)bmI * 128;
    const int bn = bnI * 128;

    const int tid = threadIdx.x;
    const int lane = tid & 63;
    const int w = tid >> 6;
    const int quad = lane >> 4;
    const int cl = lane & 15;
    const int srow = w * 16 + (lane >> 2);
    const int scol = (lane & 3) * 8;
    const int lds_off = w * 512 + lane * 8;
    const int wr = (w >> 1) * 64, wc = (w & 1) * 64;

    const ushort_t* W = z ? wq : wkv;

    long ab[2];
#pragma unroll
    for (int p = 0; p < 2; p++) {
        long gr = bm + p * 64 + srow;
        if (z == 0) ab[p] = gr * HDIM;
        else {
            int b_ = (int)(gr >> 9);
            int src = idx[(b_ << 9) + ((int)gr & 511)];
            ab[p] = ((long)(b_ << 10) + src) * HDIM;
        }
    }

    f32x4 acc[4][4] = {};

    for (int k0 = 0; k0 < HDIM; k0 += 32) {
#pragma unroll
        for (int p = 0; p < 2; p++) {
            gl_lds16(hbf + ab[p] + k0 + scol, &As[p * 2048 + lds_off]);
            gl_lds16(W + ((long)(bn + p * 64 + srow)) * HDIM + k0 + scol, &Bs[p * 2048 + lds_off]);
        }
        __syncthreads();
        bf16x8 af[4], bfr[4];
#pragma unroll
        for (int mt = 0; mt < 4; mt++)
            af[mt] = *(const bf16x8*)&As[(wr + mt * 16 + cl) * 32 + quad * 8];
#pragma unroll
        for (int nt = 0; nt < 4; nt++)
            bfr[nt] = *(const bf16x8*)&Bs[(wc + nt * 16 + cl) * 32 + quad * 8];
#pragma unroll
        for (int mt = 0; mt < 4; mt++)
#pragma unroll
            for (int nt = 0; nt < 4; nt++)
                acc[mt][nt] = __builtin_amdgcn_mfma_f32_16x16x32_bf16(af[mt], bfr[nt], acc[mt][nt], 0, 0, 0);
        __syncthreads();
    }

    if (z == 1) {
        // Q epilogue: zero invalid rows, +bias, scale
#pragma unroll
        for (int nt = 0; nt < 4; nt++) {
            int col = bn + wc + nt * 16 + cl;
            float bvq = bq[col];
#pragma unroll
            for (int mt = 0; mt < 4; mt++) {
                long row = bm + wr + mt * 16 + quad * 4;
#pragma unroll
                for (int r = 0; r < 4; r++) {
                    float vm = (float)valid[row + r];
                    qp[(row + r) * HDIM + col] = f2bf((acc[mt][nt][r] * vm + bvq) * QSCALE);
                }
            }
        }
    } else if (bn < 1024) {
        // K epilogue
#pragma unroll
        for (int nt = 0; nt < 4; nt++) {
            int col = bn + wc + nt * 16 + cl;
            float bvk = bk[col];
#pragma unroll
            for (int mt = 0; mt < 4; mt++) {
                long row = bm + wr + mt * 16 + quad * 4;
#pragma unroll
                for (int r = 0; r < 4; r++)
                    kp[(row + r) * HDIM + col] = f2bf(acc[mt][nt][r] + bvk);
            }
        }
    } else {
        // V epilogue: 2-pass LDS transpose (64 cols/pass), coalesced V^T store
        ushort_t* Lt = pool;
        long b_ = bm >> 10, s0 = bm & 1023;
#pragma unroll
        for (int p2 = 0; p2 < 2; p2++) {
            if ((w & 1) == p2) {   // waves with wc == p2*64 own these 64 cols
#pragma unroll
                for (int nt = 0; nt < 4; nt++) {
                    int cloc = nt * 16 + cl;                  // 0..63 within pass
                    float bvv = bv[bn - 1024 + p2 * 64 + cloc];
#pragma unroll
                    for (int mt = 0; mt < 4; mt++) {
                        int row0 = wr + mt * 16 + quad * 4;
#pragma unroll
                        for (int r = 0; r < 4; r++)
                            Lt[cloc * LT_PITCH + row0 + r] = f2bf(acc[mt][nt][r] + bvv);
                    }
                }
            }
            __syncthreads();
            int c2 = tid >> 2, quarter = tid & 3;             // 64 cols x 4 quarters
            long gbase = ((b_ << 10) + (bn - 1024) + p2 * 64 + c2) * 1024 + s0 + quarter * 32;
            const ushort_t* src = Lt + c2 * LT_PITCH + quarter * 32;
#pragma unroll
            for (int q8 = 0; q8 < 4; q8++)
                *(bf16x8*)(vt + gbase + q8 * 8) = *(const bf16x8*)(src + q8 * 8);
            __syncthreads();   // before pass 1 overwrites Lt
        }
    }
}

// ---------------- kernel 2: flash attention, deferred softmax ---------------
// grid (qt=4, h=16, b=8), 512 thr. Scores bounded => exp without max-subtract;
// P = 2^(s') with log2e folded into Q scale; l reduced once at the end.
#define P_PITCH 72
__global__ __launch_bounds__(512, 4) void attn_kernel(
    const ushort_t* __restrict__ qp, const ushort_t* __restrict__ kp,
    const ushort_t* __restrict__ vt, const float* __restrict__ mask,
    float* __restrict__ out) {
    __shared__ __align__(16) ushort_t ks[2][2 * 64 * 32];
    __shared__ __align__(16) ushort_t vs[2][2 * 64 * 32];
    __shared__ __align__(16) ushort_t ps[8][16 * P_PITCH];
    const int tid = threadIdx.x;
    const int lane = tid & 63;
    const int w = tid >> 6;
    const int quad = lane >> 4;
    const int cl = lane & 15;
    const int qt = blockIdx.x, h = blockIdx.y, b = blockIdx.z;

    const int skk = tid >> 8;
    const int ss  = (tid & 255) >> 2;
    const int sc8 = (tid & 3) * 8;
    const int lds_off = tid * 8;

    const long kbase = (long)b * S_LEN;
    const long vbase = (long)b * 1024 + h * HEAD_D;

    const long qrow = (long)b * KSEL + qt * 128 + w * 16 + cl;
    bf16x8 aq[2];
#pragma unroll
    for (int kk = 0; kk < 2; kk++)
        aq[kk] = *(const bf16x8*)(qp + qrow * HDIM + h * HEAD_D + kk * 32 + quad * 8);

    f32x4 O[4] = {};
    float l_r[4] = {0.f, 0.f, 0.f, 0.f};

    gl_lds16(kp + (kbase + ss) * (long)HDIM + h * HEAD_D + skk * 32 + sc8, &ks[0][lds_off]);
    gl_lds16(vt + (vbase + ss) * (long)S_LEN + skk * 32 + sc8, &vs[0][lds_off]);

    for (int c = 0; c < S_LEN / 64; c++) {
        __asm__ volatile("s_waitcnt vmcnt(0)" ::: "memory");
        __syncthreads();
        if (c + 1 < S_LEN / 64) {
            int nb = (c + 1) & 1;
            gl_lds16(kp + (kbase + (c + 1) * 64 + ss) * (long)HDIM + h * HEAD_D + skk * 32 + sc8,
                     &ks[nb][lds_off]);
            gl_lds16(vt + (vbase + ss) * (long)S_LEN + (c + 1) * 64 + skk * 32 + sc8,
                     &vs[nb][lds_off]);
        }
        const ushort_t* kbuf = ks[c & 1];
        const ushort_t* vbuf = vs[c & 1];

        // QK^T (Q pre-scaled by log2e/8)
        f32x4 sc[4] = {};
#pragma unroll
        for (int kk = 0; kk < 2; kk++) {
#pragma unroll
            for (int nt = 0; nt < 4; nt++) {
                bf16x8 bk8 = *(const bf16x8*)&kbuf[kk * 2048 + (nt * 16 + cl) * 32 + quad * 8];
                sc[nt] = __builtin_amdgcn_mfma_f32_16x16x32_bf16(aq[kk], bk8, sc[nt], 0, 0, 0);
            }
        }
        // P = 2^(s + mask*log2e); accumulate l locally
#pragma unroll
        for (int nt = 0; nt < 4; nt++) {
            float mv = mask[b * S_LEN + c * 64 + nt * 16 + cl] * 1.44269504f;
#pragma unroll
            for (int r = 0; r < 4; r++) {
                float p_ = __builtin_amdgcn_exp2f(sc[nt][r] + mv);
                sc[nt][r] = p_;
                l_r[r] += p_;
            }
        }

        // P -> LDS (C-layout write), re-read in A-layout (per-wave region)
#pragma unroll
        for (int nt = 0; nt < 4; nt++)
#pragma unroll
            for (int r = 0; r < 4; r++)
                ps[w][(quad * 4 + r) * P_PITCH + nt * 16 + cl] = f2bf(sc[nt][r]);

        __asm__ volatile("s_waitcnt lgkmcnt(0)" ::: "memory");

        // PV
#pragma unroll
        for (int kk = 0; kk < 2; kk++) {
            bf16x8 ap = *(const bf16x8*)&ps[w][cl * P_PITCH + kk * 32 + quad * 8];
#pragma unroll
            for (int dt = 0; dt < 4; dt++) {
                bf16x8 bv8 = *(const bf16x8*)&vbuf[kk * 2048 + (dt * 16 + cl) * 32 + quad * 8];
                O[dt] = __builtin_amdgcn_mfma_f32_16x16x32_bf16(ap, bv8, O[dt], 0, 0, 0);
            }
        }
    }

#pragma unroll
    for (int r = 0; r < 4; r++) {
        float s0 = l_r[r];
#pragma unroll
        for (int d = 1; d < 16; d <<= 1) s0 += __shfl_xor(s0, d, 64);
        l_r[r] = s0;
    }

    const long orow0 = (long)b * KSEL + qt * 128 + w * 16 + quad * 4;
#pragma unroll
    for (int dt = 0; dt < 4; dt++) {
        int col = h * HEAD_D + dt * 16 + cl;
#pragma unroll
        for (int r = 0; r < 4; r++)
            out[(orow0 + r) * HDIM + col] = O[dt][r] / l_r[r];
    }
}

// ---------------- launch ----------------------------------------------------
extern "C" void kernel_launch(void* const* d_in, const int* in_sizes, int n_in,
                              void* d_out, int out_size, void* d_ws, size_t ws_size,
                              hipStream_t stream) {
    const float* hidden = (const float*)d_in[0];
    const float* mask   = (const float*)d_in[1];
    const int*   remain = (const int*)d_in[2];
    const float* Wq = (const float*)d_in[3];
    const float* bq = (const float*)d_in[4];
    const float* Wk = (const float*)d_in[5];
    const float* bk = (const float*)d_in[6];
    const float* Wv = (const float*)d_in[7];
    const float* bv = (const float*)d_in[8];
    float* out = (float*)d_out;

    // ws (~64.8MB): idx 16K | valid 16K | hbf 16.78M | wqb 2M | wkb 2M | wvb 2M
    //             | qp 8.39M | kp 16.78M | vt 16.78M     (wkb||wvb contiguous!)
    char* ws = (char*)d_ws;
    size_t off = 0;
    int* idx   = (int*)(ws + off); off += 16384;
    int* valid = (int*)(ws + off); off += 16384;
    ushort_t* hbf = (ushort_t*)(ws + off); off += (size_t)BATCH * S_LEN * HDIM * 2;
    ushort_t* wqb = (ushort_t*)(ws + off); off += (size_t)HDIM * HDIM * 2;
    ushort_t* wkb = (ushort_t*)(ws + off); off += (size_t)HDIM * HDIM * 2;
    ushort_t* wvb = (ushort_t*)(ws + off); off += (size_t)HDIM * HDIM * 2;
    ushort_t* qp  = (ushort_t*)(ws + off); off += (size_t)BATCH * KSEL * HDIM * 2;
    ushort_t* kp  = (ushort_t*)(ws + off); off += (size_t)BATCH * S_LEN * HDIM * 2;
    ushort_t* vt  = (ushort_t*)(ws + off); off += (size_t)BATCH * S_LEN * HDIM * 2;

    prep_kernel<<<2824, 1024, 0, stream>>>(hidden, Wq, Wk, Wv, remain,
                                           hbf, wqb, wkb, wvb, idx, valid);
    gemm_fused<<<1280, 256, 0, stream>>>(hbf, wkb, wqb, bk, bv, bq,
                                         idx, valid, kp, vt, qp);
    attn_kernel<<<dim3(4, NHEADS, BATCH), 512, 0, stream>>>(qp, kp, vt, mask, out);
}

// Round 8
// 204.437 us; speedup vs baseline: 1.0839x; 1.0839x over previous
//
#include <hip/hip_runtime.h>
#include <hip/hip_bf16.h>
#include <stdint.h>

#define S_LEN 1024
#define HDIM  1024
#define NHEADS 16
#define HEAD_D 64
#define KSEL  512
#define BATCH 8

typedef unsigned short ushort_t;
typedef __attribute__((ext_vector_type(8))) __bf16 bf16x8;
typedef __attribute__((ext_vector_type(4))) float  f32x4;

typedef const __attribute__((address_space(1))) void cg_void;
typedef __attribute__((address_space(3))) void lds_void;

__device__ __forceinline__ void gl_lds16(const void* g, void* l) {
    __builtin_amdgcn_global_load_lds((cg_void*)g, (lds_void*)l, 16, 0, 0);
}

// round-to-nearest-even f32 -> bf16 (finite inputs only)
__device__ __forceinline__ ushort_t f2bf(float f) {
    union { float f; unsigned int i; } x; x.f = f;
    unsigned int r = (x.i + 0x7fffu + ((x.i >> 16) & 1u)) >> 16;
    return (ushort_t)r;
}

// ---------------- kernel 0: prep = cvt(hidden,Wq,Wk,Wv) + compact -----------
// blocks 0..2815: fp32->bf16 (1024 thr x 1 float4). blocks 2816..2823: compact.
__global__ __launch_bounds__(1024) void prep_kernel(
    const float* __restrict__ hidden, const float* __restrict__ wq,
    const float* __restrict__ wk, const float* __restrict__ wv,
    const int* __restrict__ remain,
    ushort_t* __restrict__ hbf, ushort_t* __restrict__ wqb,
    ushort_t* __restrict__ wkb, ushort_t* __restrict__ wvb,
    int* __restrict__ idx, int* __restrict__ valid) {
    __shared__ int wsum[16];
    __shared__ int woff[17];
    int blk = blockIdx.x;
    if (blk < 2816) {
        const float* s; ushort_t* d; int base;
        if (blk < 2048)      { s = hidden; d = hbf; base = blk; }
        else if (blk < 2304) { s = wq; d = wqb; base = blk - 2048; }
        else if (blk < 2560) { s = wk; d = wkb; base = blk - 2304; }
        else                 { s = wv; d = wvb; base = blk - 2560; }
        int i = base * 1024 + threadIdx.x;
        float4 v = ((const float4*)s)[i];
        ushort4 o;
        o.x = f2bf(v.x); o.y = f2bf(v.y); o.z = f2bf(v.z); o.w = f2bf(v.w);
        ((ushort4*)d)[i] = o;
    } else {
        int b = blk - 2816, t = threadIdx.x;
        int r = remain[b * S_LEN + t];
        unsigned long long m = __ballot(r != 0);
        int lane = t & 63, w = t >> 6;
        int pre = __popcll(m & ((1ull << lane) - 1ull));
        if (lane == 0) wsum[w] = __popcll(m);
        __syncthreads();
        if (t == 0) { int a = 0; for (int i = 0; i < 16; i++) { woff[i] = a; a += wsum[i]; } woff[16] = a; }
        __syncthreads();
        int tot = woff[16];
        int onesBefore = woff[w] + pre;
        int slot = r ? onesBefore : (tot + (t - onesBefore));
        if (slot < KSEL) { idx[b * KSEL + slot] = t; valid[b * KSEL + slot] = r; }
    }
}

// ---------------- kernel 1: fused K/V/Q projection GEMM ---------------------
// flat grid 1280. blocks 0..1023: C[8192][2048] = hbf @ [Wk;Wv]^T, XCD-swizzled
// (i&7 = XCD; each XCD owns 8 A-strips -> A fetched on one XCD only).
// n<1024 -> kp (K); n>=1024 -> vt (V^T via 2-pass LDS transpose, coalesced).
// blocks 1024..1279: Q on gathered rows, epilogue (acc*valid + bq)*QSCALE.
// QSCALE folds 1/sqrt(64) and log2(e) (attn uses exp2).
// NOTE: __launch_bounds__(256,4): (256,5) forced VGPR<=48 -> scratch spills
// (WRITE_SIZE 41->118MB, dur 72->94us). VGPR cap 128 removes spill pressure.
#define QSCALE 0.1803368801111244f
#define LT_PITCH 136
__global__ __launch_bounds__(256, 4) void gemm_fused(
    const ushort_t* __restrict__ hbf, const ushort_t* __restrict__ wkv,
    const ushort_t* __restrict__ wq,
    const float* __restrict__ bk, const float* __restrict__ bv,
    const float* __restrict__ bq,
    const int* __restrict__ idx, const int* __restrict__ valid,
    ushort_t* __restrict__ kp, ushort_t* __restrict__ vt, ushort_t* __restrict__ qp) {
    __shared__ __align__(16) ushort_t pool[64 * LT_PITCH];   // 17408 B
    ushort_t* As = pool;           // 4096 elems
    ushort_t* Bs = pool + 4096;    // 4096 elems
    const int i = blockIdx.x;
    int z, bmI, bnI;
    if (i < 1024) { z = 0; int x = i & 7, j = i >> 3; bmI = x * 8 + (j >> 4); bnI = j & 15; }
    else          { z = 1; int q = i - 1024;          bmI = q >> 3;           bnI = q & 7;  }
    const long bm = (long)bmI * 128;
    const int bn = bnI * 128;

    const int tid = threadIdx.x;
    const int lane = tid & 63;
    const int w = tid >> 6;
    const int quad = lane >> 4;
    const int cl = lane & 15;
    const int srow = w * 16 + (lane >> 2);
    const int scol = (lane & 3) * 8;
    const int lds_off = w * 512 + lane * 8;
    const int wr = (w >> 1) * 64, wc = (w & 1) * 64;

    const ushort_t* W = z ? wq : wkv;

    long ab[2];
#pragma unroll
    for (int p = 0; p < 2; p++) {
        long gr = bm + p * 64 + srow;
        if (z == 0) ab[p] = gr * HDIM;
        else {
            int b_ = (int)(gr >> 9);
            int src = idx[(b_ << 9) + ((int)gr & 511)];
            ab[p] = ((long)(b_ << 10) + src) * HDIM;
        }
    }

    f32x4 acc[4][4] = {};

    for (int k0 = 0; k0 < HDIM; k0 += 32) {
#pragma unroll
        for (int p = 0; p < 2; p++) {
            gl_lds16(hbf + ab[p] + k0 + scol, &As[p * 2048 + lds_off]);
            gl_lds16(W + ((long)(bn + p * 64 + srow)) * HDIM + k0 + scol, &Bs[p * 2048 + lds_off]);
        }
        __syncthreads();
        bf16x8 af[4], bfr[4];
#pragma unroll
        for (int mt = 0; mt < 4; mt++)
            af[mt] = *(const bf16x8*)&As[(wr + mt * 16 + cl) * 32 + quad * 8];
#pragma unroll
        for (int nt = 0; nt < 4; nt++)
            bfr[nt] = *(const bf16x8*)&Bs[(wc + nt * 16 + cl) * 32 + quad * 8];
#pragma unroll
        for (int mt = 0; mt < 4; mt++)
#pragma unroll
            for (int nt = 0; nt < 4; nt++)
                acc[mt][nt] = __builtin_amdgcn_mfma_f32_16x16x32_bf16(af[mt], bfr[nt], acc[mt][nt], 0, 0, 0);
        __syncthreads();
    }

    if (z == 1) {
        // Q epilogue: zero invalid rows, +bias, scale
#pragma unroll
        for (int nt = 0; nt < 4; nt++) {
            int col = bn + wc + nt * 16 + cl;
            float bvq = bq[col];
#pragma unroll
            for (int mt = 0; mt < 4; mt++) {
                long row = bm + wr + mt * 16 + quad * 4;
#pragma unroll
                for (int r = 0; r < 4; r++) {
                    float vm = (float)valid[row + r];
                    qp[(row + r) * HDIM + col] = f2bf((acc[mt][nt][r] * vm + bvq) * QSCALE);
                }
            }
        }
    } else if (bn < 1024) {
        // K epilogue
#pragma unroll
        for (int nt = 0; nt < 4; nt++) {
            int col = bn + wc + nt * 16 + cl;
            float bvk = bk[col];
#pragma unroll
            for (int mt = 0; mt < 4; mt++) {
                long row = bm + wr + mt * 16 + quad * 4;
#pragma unroll
                for (int r = 0; r < 4; r++)
                    kp[(row + r) * HDIM + col] = f2bf(acc[mt][nt][r] + bvk);
            }
        }
    } else {
        // V epilogue: 2-pass LDS transpose (64 cols/pass), coalesced V^T store
        ushort_t* Lt = pool;
        long b_ = bm >> 10, s0 = bm & 1023;
#pragma unroll
        for (int p2 = 0; p2 < 2; p2++) {
            if ((w & 1) == p2) {   // waves with wc == p2*64 own these 64 cols
#pragma unroll
                for (int nt = 0; nt < 4; nt++) {
                    int cloc = nt * 16 + cl;                  // 0..63 within pass
                    float bvv = bv[bn - 1024 + p2 * 64 + cloc];
#pragma unroll
                    for (int mt = 0; mt < 4; mt++) {
                        int row0 = wr + mt * 16 + quad * 4;
#pragma unroll
                        for (int r = 0; r < 4; r++)
                            Lt[cloc * LT_PITCH + row0 + r] = f2bf(acc[mt][nt][r] + bvv);
                    }
                }
            }
            __syncthreads();
            int c2 = tid >> 2, quarter = tid & 3;             // 64 cols x 4 quarters
            long gbase = ((b_ << 10) + (bn - 1024) + p2 * 64 + c2) * 1024 + s0 + quarter * 32;
            const ushort_t* src = Lt + c2 * LT_PITCH + quarter * 32;
#pragma unroll
            for (int q8 = 0; q8 < 4; q8++)
                *(bf16x8*)(vt + gbase + q8 * 8) = *(const bf16x8*)(src + q8 * 8);
            __syncthreads();   // before pass 1 overwrites Lt
        }
    }
}

// ---------------- kernel 2: flash attention, deferred softmax ---------------
// grid (qt=4, h=16, b=8), 512 thr. Scores bounded => exp without max-subtract;
// P = 2^(s') with log2e folded into Q scale; l reduced once at the end.
#define P_PITCH 72
__global__ __launch_bounds__(512, 4) void attn_kernel(
    const ushort_t* __restrict__ qp, const ushort_t* __restrict__ kp,
    const ushort_t* __restrict__ vt, const float* __restrict__ mask,
    float* __restrict__ out) {
    __shared__ __align__(16) ushort_t ks[2][2 * 64 * 32];
    __shared__ __align__(16) ushort_t vs[2][2 * 64 * 32];
    __shared__ __align__(16) ushort_t ps[8][16 * P_PITCH];
    const int tid = threadIdx.x;
    const int lane = tid & 63;
    const int w = tid >> 6;
    const int quad = lane >> 4;
    const int cl = lane & 15;
    const int qt = blockIdx.x, h = blockIdx.y, b = blockIdx.z;

    const int skk = tid >> 8;
    const int ss  = (tid & 255) >> 2;
    const int sc8 = (tid & 3) * 8;
    const int lds_off = tid * 8;

    const long kbase = (long)b * S_LEN;
    const long vbase = (long)b * 1024 + h * HEAD_D;

    const long qrow = (long)b * KSEL + qt * 128 + w * 16 + cl;
    bf16x8 aq[2];
#pragma unroll
    for (int kk = 0; kk < 2; kk++)
        aq[kk] = *(const bf16x8*)(qp + qrow * HDIM + h * HEAD_D + kk * 32 + quad * 8);

    f32x4 O[4] = {};
    float l_r[4] = {0.f, 0.f, 0.f, 0.f};

    gl_lds16(kp + (kbase + ss) * (long)HDIM + h * HEAD_D + skk * 32 + sc8, &ks[0][lds_off]);
    gl_lds16(vt + (vbase + ss) * (long)S_LEN + skk * 32 + sc8, &vs[0][lds_off]);

    for (int c = 0; c < S_LEN / 64; c++) {
        __asm__ volatile("s_waitcnt vmcnt(0)" ::: "memory");
        __syncthreads();
        if (c + 1 < S_LEN / 64) {
            int nb = (c + 1) & 1;
            gl_lds16(kp + (kbase + (c + 1) * 64 + ss) * (long)HDIM + h * HEAD_D + skk * 32 + sc8,
                     &ks[nb][lds_off]);
            gl_lds16(vt + (vbase + ss) * (long)S_LEN + (c + 1) * 64 + skk * 32 + sc8,
                     &vs[nb][lds_off]);
        }
        const ushort_t* kbuf = ks[c & 1];
        const ushort_t* vbuf = vs[c & 1];

        // QK^T (Q pre-scaled by log2e/8)
        f32x4 sc[4] = {};
#pragma unroll
        for (int kk = 0; kk < 2; kk++) {
#pragma unroll
            for (int nt = 0; nt < 4; nt++) {
                bf16x8 bk8 = *(const bf16x8*)&kbuf[kk * 2048 + (nt * 16 + cl) * 32 + quad * 8];
                sc[nt] = __builtin_amdgcn_mfma_f32_16x16x32_bf16(aq[kk], bk8, sc[nt], 0, 0, 0);
            }
        }
        // P = 2^(s + mask*log2e); accumulate l locally
#pragma unroll
        for (int nt = 0; nt < 4; nt++) {
            float mv = mask[b * S_LEN + c * 64 + nt * 16 + cl] * 1.44269504f;
#pragma unroll
            for (int r = 0; r < 4; r++) {
                float p_ = __builtin_amdgcn_exp2f(sc[nt][r] + mv);
                sc[nt][r] = p_;
                l_r[r] += p_;
            }
        }

        // P -> LDS (C-layout write), re-read in A-layout (per-wave region)
#pragma unroll
        for (int nt = 0; nt < 4; nt++)
#pragma unroll
            for (int r = 0; r < 4; r++)
                ps[w][(quad * 4 + r) * P_PITCH + nt * 16 + cl] = f2bf(sc[nt][r]);

        __asm__ volatile("s_waitcnt lgkmcnt(0)" ::: "memory");

        // PV
#pragma unroll
        for (int kk = 0; kk < 2; kk++) {
            bf16x8 ap = *(const bf16x8*)&ps[w][cl * P_PITCH + kk * 32 + quad * 8];
#pragma unroll
            for (int dt = 0; dt < 4; dt++) {
                bf16x8 bv8 = *(const bf16x8*)&vbuf[kk * 2048 + (dt * 16 + cl) * 32 + quad * 8];
                O[dt] = __builtin_amdgcn_mfma_f32_16x16x32_bf16(ap, bv8, O[dt], 0, 0, 0);
            }
        }
    }

#pragma unroll
    for (int r = 0; r < 4; r++) {
        float s0 = l_r[r];
#pragma unroll
        for (int d = 1; d < 16; d <<= 1) s0 += __shfl_xor(s0, d, 64);
        l_r[r] = s0;
    }

    const long orow0 = (long)b * KSEL + qt * 128 + w * 16 + quad * 4;
#pragma unroll
    for (int dt = 0; dt < 4; dt++) {
        int col = h * HEAD_D + dt * 16 + cl;
#pragma unroll
        for (int r = 0; r < 4; r++)
            out[(orow0 + r) * HDIM + col] = O[dt][r] / l_r[r];
    }
}

// ---------------- launch ----------------------------------------------------
extern "C" void kernel_launch(void* const* d_in, const int* in_sizes, int n_in,
                              void* d_out, int out_size, void* d_ws, size_t ws_size,
                              hipStream_t stream) {
    const float* hidden = (const float*)d_in[0];
    const float* mask   = (const float*)d_in[1];
    const int*   remain = (const int*)d_in[2];
    const float* Wq = (const float*)d_in[3];
    const float* bq = (const float*)d_in[4];
    const float* Wk = (const float*)d_in[5];
    const float* bk = (const float*)d_in[6];
    const float* Wv = (const float*)d_in[7];
    const float* bv = (const float*)d_in[8];
    float* out = (float*)d_out;

    // ws (~64.8MB): idx 16K | valid 16K | hbf 16.78M | wqb 2M | wkb 2M | wvb 2M
    //             | qp 8.39M | kp 16.78M | vt 16.78M     (wkb||wvb contiguous!)
    char* ws = (char*)d_ws;
    size_t off = 0;
    int* idx   = (int*)(ws + off); off += 16384;
    int* valid = (int*)(ws + off); off += 16384;
    ushort_t* hbf = (ushort_t*)(ws + off); off += (size_t)BATCH * S_LEN * HDIM * 2;
    ushort_t* wqb = (ushort_t*)(ws + off); off += (size_t)HDIM * HDIM * 2;
    ushort_t* wkb = (ushort_t*)(ws + off); off += (size_t)HDIM * HDIM * 2;
    ushort_t* wvb = (ushort_t*)(ws + off); off += (size_t)HDIM * HDIM * 2;
    ushort_t* qp  = (ushort_t*)(ws + off); off += (size_t)BATCH * KSEL * HDIM * 2;
    ushort_t* kp  = (ushort_t*)(ws + off); off += (size_t)BATCH * S_LEN * HDIM * 2;
    ushort_t* vt  = (ushort_t*)(ws + off); off += (size_t)BATCH * S_LEN * HDIM * 2;

    prep_kernel<<<2824, 1024, 0, stream>>>(hidden, Wq, Wk, Wv, remain,
                                           hbf, wqb, wkb, wvb, idx, valid);
    gemm_fused<<<1280, 256, 0, stream>>>(hbf, wkb, wqb, bk, bv, bq,
                                         idx, valid, kp, vt, qp);
    attn_kernel<<<dim3(4, NHEADS, BATCH), 512, 0, stream>>>(qp, kp, vt, mask, out);
}

// Round 9
// 199.173 us; speedup vs baseline: 1.1125x; 1.0264x over previous
//
#include <hip/hip_runtime.h>
#include <hip/hip_bf16.h>
#include <stdint.h>

#define S_LEN 1024
#define HDIM  1024
#define NHEADS 16
#define HEAD_D 64
#define KSEL  512
#define BATCH 8

typedef unsigned short ushort_t;
typedef __attribute__((ext_vector_type(8))) __bf16 bf16x8;
typedef __attribute__((ext_vector_type(4))) float  f32x4;

typedef const __attribute__((address_space(1))) void cg_void;
typedef __attribute__((address_space(3))) void lds_void;

__device__ __forceinline__ void gl_lds16(const void* g, void* l) {
    __builtin_amdgcn_global_load_lds((cg_void*)g, (lds_void*)l, 16, 0, 0);
}

// round-to-nearest-even f32 -> bf16 (finite inputs only)
__device__ __forceinline__ ushort_t f2bf(float f) {
    union { float f; unsigned int i; } x; x.f = f;
    unsigned int r = (x.i + 0x7fffu + ((x.i >> 16) & 1u)) >> 16;
    return (ushort_t)r;
}

// ---------------- kernel 0: prep = cvt(hidden,Wq,Wk,Wv) + compact -----------
__global__ __launch_bounds__(1024) void prep_kernel(
    const float* __restrict__ hidden, const float* __restrict__ wq,
    const float* __restrict__ wk, const float* __restrict__ wv,
    const int* __restrict__ remain,
    ushort_t* __restrict__ hbf, ushort_t* __restrict__ wqb,
    ushort_t* __restrict__ wkb, ushort_t* __restrict__ wvb,
    int* __restrict__ idx, int* __restrict__ valid) {
    __shared__ int wsum[16];
    __shared__ int woff[17];
    int blk = blockIdx.x;
    if (blk < 2816) {
        const float* s; ushort_t* d; int base;
        if (blk < 2048)      { s = hidden; d = hbf; base = blk; }
        else if (blk < 2304) { s = wq; d = wqb; base = blk - 2048; }
        else if (blk < 2560) { s = wk; d = wkb; base = blk - 2304; }
        else                 { s = wv; d = wvb; base = blk - 2560; }
        int i = base * 1024 + threadIdx.x;
        float4 v = ((const float4*)s)[i];
        ushort4 o;
        o.x = f2bf(v.x); o.y = f2bf(v.y); o.z = f2bf(v.z); o.w = f2bf(v.w);
        ((ushort4*)d)[i] = o;
    } else {
        int b = blk - 2816, t = threadIdx.x;
        int r = remain[b * S_LEN + t];
        unsigned long long m = __ballot(r != 0);
        int lane = t & 63, w = t >> 6;
        int pre = __popcll(m & ((1ull << lane) - 1ull));
        if (lane == 0) wsum[w] = __popcll(m);
        __syncthreads();
        if (t == 0) { int a = 0; for (int i = 0; i < 16; i++) { woff[i] = a; a += wsum[i]; } woff[16] = a; }
        __syncthreads();
        int tot = woff[16];
        int onesBefore = woff[w] + pre;
        int slot = r ? onesBefore : (tot + (t - onesBefore));
        if (slot < KSEL) { idx[b * KSEL + slot] = t; valid[b * KSEL + slot] = r; }
    }
}

// ---------------- kernel 1: fused K/V/Q projection GEMM, BK=64 --------------
// flat grid 1280. blocks 0..1023: C[8192][2048] = hbf @ [Wk;Wv]^T, XCD-swizzled.
// BK=64 staged as two BK=32 halves -> 16 barriers instead of 32.
// n<1024 -> kp; n>=1024 -> vt (V^T via 2-pass LDS transpose, coalesced).
// blocks 1024..1279: Q on gathered rows, epilogue (acc*valid + bq)*QSCALE.
// NOTE: __launch_bounds__(256,4); (256,5) forced VGPR<=48 -> scratch spills.
#define QSCALE 0.1803368801111244f
#define LT_PITCH 136
__global__ __launch_bounds__(256, 4) void gemm_fused(
    const ushort_t* __restrict__ hbf, const ushort_t* __restrict__ wkv,
    const ushort_t* __restrict__ wq,
    const float* __restrict__ bk, const float* __restrict__ bv,
    const float* __restrict__ bq,
    const int* __restrict__ idx, const int* __restrict__ valid,
    ushort_t* __restrict__ kp, ushort_t* __restrict__ vt, ushort_t* __restrict__ qp) {
    __shared__ __align__(16) ushort_t pool[16384];   // 32 KB: As 8192 | Bs 8192
    ushort_t* As = pool;
    ushort_t* Bs = pool + 8192;
    const int i = blockIdx.x;
    int z, bmI, bnI;
    if (i < 1024) { z = 0; int x = i & 7, j = i >> 3; bmI = x * 8 + (j >> 4); bnI = j & 15; }
    else          { z = 1; int q = i - 1024;          bmI = q >> 3;           bnI = q & 7;  }
    const long bm = (long)bmI * 128;
    const int bn = bnI * 128;

    const int tid = threadIdx.x;
    const int lane = tid & 63;
    const int w = tid >> 6;
    const int quad = lane >> 4;
    const int cl = lane & 15;
    const int srow = w * 16 + (lane >> 2);
    const int scol = (lane & 3) * 8;
    const int lds_off = w * 512 + lane * 8;
    const int wr = (w >> 1) * 64, wc = (w & 1) * 64;

    const ushort_t* W = z ? wq : wkv;

    long ab[2];
#pragma unroll
    for (int p = 0; p < 2; p++) {
        long gr = bm + p * 64 + srow;
        if (z == 0) ab[p] = gr * HDIM;
        else {
            int b_ = (int)(gr >> 9);
            int src = idx[(b_ << 9) + ((int)gr & 511)];
            ab[p] = ((long)(b_ << 10) + src) * HDIM;
        }
    }

    f32x4 acc[4][4] = {};

    for (int k0 = 0; k0 < HDIM; k0 += 64) {
#pragma unroll
        for (int p = 0; p < 2; p++)
#pragma unroll
            for (int hh = 0; hh < 2; hh++) {
                gl_lds16(hbf + ab[p] + k0 + hh * 32 + scol, &As[hh * 4096 + p * 2048 + lds_off]);
                gl_lds16(W + ((long)(bn + p * 64 + srow)) * HDIM + k0 + hh * 32 + scol,
                         &Bs[hh * 4096 + p * 2048 + lds_off]);
            }
        __syncthreads();
#pragma unroll
        for (int hh = 0; hh < 2; hh++) {
            bf16x8 af[4], bfr[4];
#pragma unroll
            for (int mt = 0; mt < 4; mt++)
                af[mt] = *(const bf16x8*)&As[hh * 4096 + (wr + mt * 16 + cl) * 32 + quad * 8];
#pragma unroll
            for (int nt = 0; nt < 4; nt++)
                bfr[nt] = *(const bf16x8*)&Bs[hh * 4096 + (wc + nt * 16 + cl) * 32 + quad * 8];
#pragma unroll
            for (int mt = 0; mt < 4; mt++)
#pragma unroll
                for (int nt = 0; nt < 4; nt++)
                    acc[mt][nt] = __builtin_amdgcn_mfma_f32_16x16x32_bf16(af[mt], bfr[nt], acc[mt][nt], 0, 0, 0);
        }
        __syncthreads();
    }

    if (z == 1) {
#pragma unroll
        for (int nt = 0; nt < 4; nt++) {
            int col = bn + wc + nt * 16 + cl;
            float bvq = bq[col];
#pragma unroll
            for (int mt = 0; mt < 4; mt++) {
                long row = bm + wr + mt * 16 + quad * 4;
#pragma unroll
                for (int r = 0; r < 4; r++) {
                    float vm = (float)valid[row + r];
                    qp[(row + r) * HDIM + col] = f2bf((acc[mt][nt][r] * vm + bvq) * QSCALE);
                }
            }
        }
    } else if (bn < 1024) {
#pragma unroll
        for (int nt = 0; nt < 4; nt++) {
            int col = bn + wc + nt * 16 + cl;
            float bvk = bk[col];
#pragma unroll
            for (int mt = 0; mt < 4; mt++) {
                long row = bm + wr + mt * 16 + quad * 4;
#pragma unroll
                for (int r = 0; r < 4; r++)
                    kp[(row + r) * HDIM + col] = f2bf(acc[mt][nt][r] + bvk);
            }
        }
    } else {
        // V epilogue: 2-pass LDS transpose (64 cols/pass), coalesced V^T store
        ushort_t* Lt = pool;   // 8704 elems needed, fits in 16384
        long b_ = bm >> 10, s0 = bm & 1023;
#pragma unroll
        for (int p2 = 0; p2 < 2; p2++) {
            if ((w & 1) == p2) {
#pragma unroll
                for (int nt = 0; nt < 4; nt++) {
                    int cloc = nt * 16 + cl;
                    float bvv = bv[bn - 1024 + p2 * 64 + cloc];
#pragma unroll
                    for (int mt = 0; mt < 4; mt++) {
                        int row0 = wr + mt * 16 + quad * 4;
#pragma unroll
                        for (int r = 0; r < 4; r++)
                            Lt[cloc * LT_PITCH + row0 + r] = f2bf(acc[mt][nt][r] + bvv);
                    }
                }
            }
            __syncthreads();
            int c2 = tid >> 2, quarter = tid & 3;
            long gbase = ((b_ << 10) + (bn - 1024) + p2 * 64 + c2) * 1024 + s0 + quarter * 32;
            const ushort_t* src = Lt + c2 * LT_PITCH + quarter * 32;
#pragma unroll
            for (int q8 = 0; q8 < 4; q8++)
                *(bf16x8*)(vt + gbase + q8 * 8) = *(const bf16x8*)(src + q8 * 8);
            __syncthreads();
        }
    }
}

// ---------------- kernel 2: flash attention, 32 q-rows per wave -------------
// grid (qt=4, h=16, b=8), 256 thr (4 waves x 32 q-rows = 128 rows/block).
// Each K/V fragment read from LDS feeds 2 MFMA (2 m-tiles) -> ~2x fewer LDS
// cycles per FLOP (attn is LDS-throughput-bound). Deferred softmax as before.
#define P_PITCH 72   // 144B rows: 16B-aligned for b128 reads
__global__ __launch_bounds__(256, 2) void attn_kernel(
    const ushort_t* __restrict__ qp, const ushort_t* __restrict__ kp,
    const ushort_t* __restrict__ vt, const float* __restrict__ mask,
    float* __restrict__ out) {
    __shared__ __align__(16) ushort_t ks[2][4096];       // [buf][kk][s][32]
    __shared__ __align__(16) ushort_t vs[2][4096];       // [buf][kk][d][32]
    __shared__ __align__(16) ushort_t ps[4][32 * P_PITCH];
    const int tid = threadIdx.x;
    const int lane = tid & 63;
    const int w = tid >> 6;          // 0..3
    const int quad = lane >> 4;
    const int cl = lane & 15;
    const int qt = blockIdx.x, h = blockIdx.y, b = blockIdx.z;

    // staging: 256 thr x 2 issues x 16B = 8KB per array per chunk
    const int srow = tid >> 2;           // 0..63
    const int sc8 = (tid & 3) * 8;
    const int lds_off = tid * 8;         // elems; wave-uniform base + lane*16B

    const long kbase = (long)b * S_LEN;
    const long vbase = (long)b * 1024 + h * HEAD_D;

    // Q fragments (A-layout), 2 m-tiles of 16 rows each
    const long qrow0 = (long)b * KSEL + qt * 128 + w * 32;
    bf16x8 aq[2][2];
#pragma unroll
    for (int mt = 0; mt < 2; mt++)
#pragma unroll
        for (int kk = 0; kk < 2; kk++)
            aq[mt][kk] = *(const bf16x8*)(qp + (qrow0 + mt * 16 + cl) * HDIM + h * HEAD_D + kk * 32 + quad * 8);

    f32x4 O[2][4] = {};
    float l_r[2][4] = {};

    // prologue: stage chunk 0 into buffer 0 (j indexes the 32-dim half == kk)
#pragma unroll
    for (int j = 0; j < 2; j++) {
        gl_lds16(kp + (kbase + srow) * (long)HDIM + h * HEAD_D + j * 32 + sc8, &ks[0][j * 2048 + lds_off]);
        gl_lds16(vt + (vbase + srow) * (long)S_LEN + j * 32 + sc8, &vs[0][j * 2048 + lds_off]);
    }

    for (int c = 0; c < S_LEN / 64; c++) {
        __asm__ volatile("s_waitcnt vmcnt(0)" ::: "memory");
        __syncthreads();
        if (c + 1 < S_LEN / 64) {
            int nb = (c + 1) & 1;
#pragma unroll
            for (int j = 0; j < 2; j++) {
                gl_lds16(kp + (kbase + (c + 1) * 64 + srow) * (long)HDIM + h * HEAD_D + j * 32 + sc8,
                         &ks[nb][j * 2048 + lds_off]);
                gl_lds16(vt + (vbase + srow) * (long)S_LEN + (c + 1) * 64 + j * 32 + sc8,
                         &vs[nb][j * 2048 + lds_off]);
            }
        }
        const ushort_t* kbuf = ks[c & 1];
        const ushort_t* vbuf = vs[c & 1];

        // QK^T: each K-fragment feeds both m-tiles
        f32x4 sc[2][4] = {};
#pragma unroll
        for (int kk = 0; kk < 2; kk++)
#pragma unroll
            for (int nt = 0; nt < 4; nt++) {
                bf16x8 bk8 = *(const bf16x8*)&kbuf[kk * 2048 + (nt * 16 + cl) * 32 + quad * 8];
#pragma unroll
                for (int mt = 0; mt < 2; mt++)
                    sc[mt][nt] = __builtin_amdgcn_mfma_f32_16x16x32_bf16(aq[mt][kk], bk8, sc[mt][nt], 0, 0, 0);
            }

        // P = 2^(s + mask*log2e); accumulate l locally (deferred reduction)
#pragma unroll
        for (int nt = 0; nt < 4; nt++) {
            float mv = mask[b * S_LEN + c * 64 + nt * 16 + cl] * 1.44269504f;
#pragma unroll
            for (int mt = 0; mt < 2; mt++)
#pragma unroll
                for (int r = 0; r < 4; r++) {
                    float p_ = __builtin_amdgcn_exp2f(sc[mt][nt][r] + mv);
                    sc[mt][nt][r] = p_;
                    l_r[mt][r] += p_;
                }
        }

        // P -> LDS (C-layout write), rows mt*16 + quad*4 + r
#pragma unroll
        for (int mt = 0; mt < 2; mt++)
#pragma unroll
            for (int nt = 0; nt < 4; nt++)
#pragma unroll
                for (int r = 0; r < 4; r++)
                    ps[w][(mt * 16 + quad * 4 + r) * P_PITCH + nt * 16 + cl] = f2bf(sc[mt][nt][r]);

        __asm__ volatile("s_waitcnt lgkmcnt(0)" ::: "memory");

        // PV: each V-fragment feeds both m-tiles
#pragma unroll
        for (int kk = 0; kk < 2; kk++) {
            bf16x8 ap[2];
#pragma unroll
            for (int mt = 0; mt < 2; mt++)
                ap[mt] = *(const bf16x8*)&ps[w][(mt * 16 + cl) * P_PITCH + kk * 32 + quad * 8];
#pragma unroll
            for (int dt = 0; dt < 4; dt++) {
                bf16x8 bv8 = *(const bf16x8*)&vbuf[kk * 2048 + (dt * 16 + cl) * 32 + quad * 8];
#pragma unroll
                for (int mt = 0; mt < 2; mt++)
                    O[mt][dt] = __builtin_amdgcn_mfma_f32_16x16x32_bf16(ap[mt], bv8, O[mt][dt], 0, 0, 0);
            }
        }
    }

    // final l reduction over the quad's 16 lanes
#pragma unroll
    for (int mt = 0; mt < 2; mt++)
#pragma unroll
        for (int r = 0; r < 4; r++) {
            float s0 = l_r[mt][r];
#pragma unroll
            for (int d = 1; d < 16; d <<= 1) s0 += __shfl_xor(s0, d, 64);
            l_r[mt][r] = s0;
        }

#pragma unroll
    for (int mt = 0; mt < 2; mt++) {
        const long orow0 = qrow0 + mt * 16 + quad * 4;
#pragma unroll
        for (int dt = 0; dt < 4; dt++) {
            int col = h * HEAD_D + dt * 16 + cl;
#pragma unroll
            for (int r = 0; r < 4; r++)
                out[(orow0 + r) * HDIM + col] = O[mt][dt][r] / l_r[mt][r];
        }
    }
}

// ---------------- launch ----------------------------------------------------
extern "C" void kernel_launch(void* const* d_in, const int* in_sizes, int n_in,
                              void* d_out, int out_size, void* d_ws, size_t ws_size,
                              hipStream_t stream) {
    const float* hidden = (const float*)d_in[0];
    const float* mask   = (const float*)d_in[1];
    const int*   remain = (const int*)d_in[2];
    const float* Wq = (const float*)d_in[3];
    const float* bq = (const float*)d_in[4];
    const float* Wk = (const float*)d_in[5];
    const float* bk = (const float*)d_in[6];
    const float* Wv = (const float*)d_in[7];
    const float* bv = (const float*)d_in[8];
    float* out = (float*)d_out;

    // ws (~64.8MB): idx 16K | valid 16K | hbf 16.78M | wqb 2M | wkb 2M | wvb 2M
    //             | qp 8.39M | kp 16.78M | vt 16.78M     (wkb||wvb contiguous!)
    char* ws = (char*)d_ws;
    size_t off = 0;
    int* idx   = (int*)(ws + off); off += 16384;
    int* valid = (int*)(ws + off); off += 16384;
    ushort_t* hbf = (ushort_t*)(ws + off); off += (size_t)BATCH * S_LEN * HDIM * 2;
    ushort_t* wqb = (ushort_t*)(ws + off); off += (size_t)HDIM * HDIM * 2;
    ushort_t* wkb = (ushort_t*)(ws + off); off += (size_t)HDIM * HDIM * 2;
    ushort_t* wvb = (ushort_t*)(ws + off); off += (size_t)HDIM * HDIM * 2;
    ushort_t* qp  = (ushort_t*)(ws + off); off += (size_t)BATCH * KSEL * HDIM * 2;
    ushort_t* kp  = (ushort_t*)(ws + off); off += (size_t)BATCH * S_LEN * HDIM * 2;
    ushort_t* vt  = (ushort_t*)(ws + off); off += (size_t)BATCH * S_LEN * HDIM * 2;

    prep_kernel<<<2824, 1024, 0, stream>>>(hidden, Wq, Wk, Wv, remain,
                                           hbf, wqb, wkb, wvb, idx, valid);
    gemm_fused<<<1280, 256, 0, stream>>>(hbf, wkb, wqb, bk, bv, bq,
                                         idx, valid, kp, vt, qp);
    attn_kernel<<<dim3(4, NHEADS, BATCH), 256, 0, stream>>>(qp, kp, vt, mask, out);
}